// Round 1
// baseline (17875.142 us; speedup 1.0000x reference)
//
#include <hip/hip_runtime.h>
#include <stdint.h>

#define T_STEPS 8192
#define K_TAGS 1024
#define D_DIM 1024
#define START_TAG 1022
#define STOP_TAG 1023
#define NEGV (-10000.0f)
#define LOG2E 1.4426950408889634f
#define LN2 0.6931471805599453f

#define NBLK 128      // blocks in persistent CRF kernel
#define ROWS_PB 8     // K_TAGS / NBLK rows per block
#define PREV_PT 8     // prev entries per thread (128 threads per row)

// ---- agent-scope (device) 64-bit payload+tag atomics -----------------------
__device__ __forceinline__ unsigned long long ld_agent_u64(const unsigned long long* p) {
  return __hip_atomic_load(p, __ATOMIC_RELAXED, __HIP_MEMORY_SCOPE_AGENT);
}
__device__ __forceinline__ void st_agent_u64(unsigned long long* p, unsigned long long v) {
  __hip_atomic_store(p, v, __ATOMIC_RELAXED, __HIP_MEMORY_SCOPE_AGENT);
}

// ---- workspace init (runs every call; ws is NOT re-poisoned between replays)
__global__ void init_ws_kernel(unsigned long long* fvbuf, int* bmax) {
  int i = blockIdx.x * blockDim.x + threadIdx.x;
  if (i < 2 * K_TAGS) fvbuf[i] = 0ull;   // tag 0 everywhere
  if (i == 0) *bmax = 0;                 // float 0.0 bits; true max is positive
}

// ---- per-step gate: sigmoid(cat(rep[t-1],rep[t]) . w_sel) -------------------
__global__ __launch_bounds__(256) void gate_kernel(
    const float* __restrict__ reps, const float* __restrict__ wc,
    const float* __restrict__ wu, const int* __restrict__ spk,
    float* __restrict__ gate, float* __restrict__ g_term) {
  int t = blockIdx.x;
  int tid = threadIdx.x;
  const float* cur;
  const float* prv;
  if (t < T_STEPS) {
    cur = reps + (size_t)t * D_DIM;
    prv = reps + (size_t)(t > 0 ? t - 1 : 0) * D_DIM;
  } else {  // terminal block: cat(rep[T-1], rep[T-1]) with w_unchange
    cur = reps + (size_t)(T_STEPS - 1) * D_DIM;
    prv = cur;
  }
  float sc = 0.f, su = 0.f;
  for (int d = tid; d < D_DIM; d += 256) {
    float rp = prv[d], rc = cur[d];
    sc += rp * wc[d] + rc * wc[D_DIM + d];
    su += rp * wu[d] + rc * wu[D_DIM + d];
  }
#pragma unroll
  for (int off = 32; off; off >>= 1) {
    sc += __shfl_down(sc, off);
    su += __shfl_down(su, off);
  }
  __shared__ float lc[4], lu[4];
  int wid = tid >> 6;
  if ((tid & 63) == 0) { lc[wid] = sc; lu[wid] = su; }
  __syncthreads();
  if (tid == 0) {
    float dc = lc[0] + lc[1] + lc[2] + lc[3];
    float du = lu[0] + lu[1] + lu[2] + lu[3];
    if (t < T_STEPS) {
      bool uc = (t > 0) && (spk[t] != 0);
      float x = uc ? dc : du;
      gate[t] = 1.0f / (1.0f + __expf(-x));
    } else {
      *g_term = 1.0f / (1.0f + __expf(-du));
    }
  }
}

// ---- global max over elementwise max(ti, ta) (for the safe LSE shift) ------
__global__ __launch_bounds__(256) void bmax_kernel(
    const float* __restrict__ ti, const float* __restrict__ ta, int* bmax) {
  size_t i = (size_t)blockIdx.x * blockDim.x + threadIdx.x;
  size_t n = (size_t)K_TAGS * K_TAGS;
  float m = 0.f;  // clamped at 0 so int-compare atomicMax is valid
  for (size_t j = i; j < n; j += (size_t)gridDim.x * blockDim.x)
    m = fmaxf(m, fmaxf(ti[j], ta[j]));
#pragma unroll
  for (int off = 32; off; off >>= 1) m = fmaxf(m, __shfl_xor(m, off));
  if ((threadIdx.x & 63) == 0) atomicMax(bmax, __float_as_int(m));
}

// ---- persistent CRF forward scan -------------------------------------------
// 128 blocks x 1024 threads. Block b owns rows [8b, 8b+8). Thread layout:
// rloc = tid>>7 (row within block), 128 threads/row, 8 contiguous prevs each.
// ta2/df2 slices live in registers for all 8192 steps (log2-scaled).
// fv state exchanged via u64 (tag<<32 | float bits) relaxed agent atomics.
__global__ __launch_bounds__(1024) void crf_kernel(
    const float* __restrict__ feats, const float* __restrict__ ti,
    const float* __restrict__ ta, const float* __restrict__ gate,
    const float* __restrict__ g_term_p, const int* __restrict__ bmax_p,
    unsigned long long* fvbuf, float* __restrict__ out) {
  const int b = blockIdx.x;
  const int tid = threadIdx.x;
  const int lane = tid & 63;
  const int wid = tid >> 6;
  const int rloc = tid >> 7;
  const int grow = b * ROWS_PB + rloc;
  const int pr0 = (tid & 127) * PREV_PT;

  __shared__ __align__(16) float fvs[K_TAGS];
  __shared__ float wredM[16];
  __shared__ float wredS[16];
  __shared__ float m2s;

  // register-resident, log2-scaled matrix slices (constant across steps)
  float ta2[PREV_PT], df2[PREV_PT];
  {
    const size_t mb = (size_t)grow * K_TAGS + pr0;
#pragma unroll
    for (int c = 0; c < PREV_PT; ++c) {
      float a = ta[mb + c];
      float i_ = ti[mb + c];
      ta2[c] = a * LOG2E;
      df2[c] = (i_ - a) * LOG2E;
    }
  }
  const float bmax2 = __int_as_float(*bmax_p) * LOG2E;

  // publish initial state s_0 (tag 1) into slot 0
  if (tid < ROWS_PB) {
    int r = b * ROWS_PB + tid;
    float v = (r == START_TAG) ? 0.0f : NEGV * LOG2E;
    st_agent_u64(&fvbuf[r],
                 (1ull << 32) | (unsigned long long)__float_as_uint(v));
  }

  for (int t = 0; t < T_STEPS; ++t) {
    const int slot = t & 1;
    const unsigned want = (unsigned)(t + 1);
    const float g = gate[t];
    float featv = 0.f;
    if (tid < ROWS_PB)  // prefetch this step's emission for our row
      featv = feats[(size_t)t * K_TAGS + b * ROWS_PB + tid];

    // 1) gather: each thread spins on its own (payload|tag) atom
    unsigned long long* ep = &fvbuf[slot * K_TAGS + tid];
    unsigned long long u = ld_agent_u64(ep);
    while ((unsigned)(u >> 32) < want) {
      __builtin_amdgcn_s_sleep(1);
      u = ld_agent_u64(ep);
    }
    const float v = __uint_as_float((unsigned)u);

    // 2) block max of fv -> shift M2 = max(fv) + Bmax
    float m = v;
#pragma unroll
    for (int off = 32; off; off >>= 1) m = fmaxf(m, __shfl_xor(m, off));
    if (lane == 0) wredM[wid] = m;
    __syncthreads();  // S1
    if (tid == 0) {
      float mm = wredM[0];
#pragma unroll
      for (int i = 1; i < 16; ++i) mm = fmaxf(mm, wredM[i]);
      m2s = mm + bmax2;
    }
    __syncthreads();  // S2
    const float M2 = m2s;
    fvs[tid] = v - M2;
    __syncthreads();  // S3

    // 3) cells: acc += 2^(ta2 + g*df2 + fvshift)
    const float4 f0 = *reinterpret_cast<const float4*>(&fvs[pr0]);
    const float4 f1 = *reinterpret_cast<const float4*>(&fvs[pr0 + 4]);
    const float fv8[8] = {f0.x, f0.y, f0.z, f0.w, f1.x, f1.y, f1.z, f1.w};
    float acc = 0.f;
#pragma unroll
    for (int c = 0; c < PREV_PT; ++c)
      acc += exp2f(__builtin_fmaf(g, df2[c], ta2[c]) + fv8[c]);
#pragma unroll
    for (int off = 32; off; off >>= 1) acc += __shfl_xor(acc, off);
    if (lane == 0) wredS[wid] = acc;
    __syncthreads();  // S4

    // 4) finalize + publish (tag t+2) into the other slot
    if (tid < ROWS_PB) {
      float s = wredS[tid * 2] + wredS[tid * 2 + 1];
      float fvnew = M2 + __log2f(s) + featv * LOG2E;  // -inf if s==0: OK
      st_agent_u64(&fvbuf[(slot ^ 1) * K_TAGS + b * ROWS_PB + tid],
                   ((unsigned long long)(unsigned)(t + 2) << 32) |
                       (unsigned long long)__float_as_uint(fvnew));
    }
  }

  // ---- terminal LSE by block 0 ----------------------------------------------
  if (b == 0) {
    const int slot = T_STEPS & 1;  // 0
    unsigned long long* ep = &fvbuf[slot * K_TAGS + tid];
    const unsigned want = (unsigned)(T_STEPS + 1);
    unsigned long long u = ld_agent_u64(ep);
    while ((unsigned)(u >> 32) < want) {
      __builtin_amdgcn_s_sleep(1);
      u = ld_agent_u64(ep);
    }
    const float v = __uint_as_float((unsigned)u);
    const float gt = *g_term_p;
    const float tis = ti[(size_t)STOP_TAG * K_TAGS + tid];
    const float tas = ta[(size_t)STOP_TAG * K_TAGS + tid];
    const float term2 = v + (tas + gt * (tis - tas)) * LOG2E;

    float m = term2;
#pragma unroll
    for (int off = 32; off; off >>= 1) m = fmaxf(m, __shfl_xor(m, off));
    if (lane == 0) wredM[wid] = m;
    __syncthreads();
    if (tid == 0) {
      float mm = wredM[0];
#pragma unroll
      for (int i = 1; i < 16; ++i) mm = fmaxf(mm, wredM[i]);
      m2s = mm;
    }
    __syncthreads();
    const float M2 = m2s;
    float e = exp2f(term2 - M2);
#pragma unroll
    for (int off = 32; off; off >>= 1) e += __shfl_xor(e, off);
    if (lane == 0) wredS[wid] = e;
    __syncthreads();
    if (tid == 0) {
      float s = 0.f;
#pragma unroll
      for (int i = 0; i < 16; ++i) s += wredS[i];
      out[0] = (M2 + __log2f(s)) * LN2;
    }
  }
}

extern "C" void kernel_launch(void* const* d_in, const int* in_sizes, int n_in,
                              void* d_out, int out_size, void* d_ws, size_t ws_size,
                              hipStream_t stream) {
  (void)in_sizes; (void)n_in; (void)out_size; (void)ws_size;
  const float* feats = (const float*)d_in[0];
  const float* reps  = (const float*)d_in[1];
  const float* wc    = (const float*)d_in[2];
  const float* wu    = (const float*)d_in[3];
  const float* ti    = (const float*)d_in[4];
  const float* ta    = (const float*)d_in[5];
  const int*   spk   = (const int*)d_in[6];
  float* out = (float*)d_out;

  // ws layout: fvbuf[2][1024] u64 (16 KiB) | gate[8192] f32 | g_term f32 | bmax i32
  unsigned long long* fvbuf = (unsigned long long*)d_ws;
  float* gate  = (float*)((char*)d_ws + 2 * K_TAGS * sizeof(unsigned long long));
  float* gterm = gate + T_STEPS;
  int*   bmax  = (int*)(gterm + 1);

  init_ws_kernel<<<dim3(8), dim3(256), 0, stream>>>(fvbuf, bmax);
  gate_kernel<<<dim3(T_STEPS + 1), dim3(256), 0, stream>>>(reps, wc, wu, spk, gate, gterm);
  bmax_kernel<<<dim3(512), dim3(256), 0, stream>>>(ti, ta, bmax);
  crf_kernel<<<dim3(NBLK), dim3(1024), 0, stream>>>(feats, ti, ta, gate, gterm, bmax, fvbuf, out);
}

// Round 2
// 15661.655 us; speedup vs baseline: 1.1413x; 1.1413x over previous
//
#include <hip/hip_runtime.h>
#include <stdint.h>

#define T_STEPS 8192
#define K_TAGS 1024
#define D_DIM 1024
#define START_TAG 1022
#define STOP_TAG 1023
#define NEGV (-10000.0f)
#define LOG2E 1.4426950408889634f
#define LN2 0.6931471805599453f

#define NBLK 256      // blocks in persistent CRF kernel
#define ROWS_PB 4     // K_TAGS / NBLK rows per block; one WAVE per row
#define C8 8          // float2 cell-pairs per lane (16 prev cells / lane)

// ---- agent-scope (device) 64-bit payload+tag atomics -----------------------
__device__ __forceinline__ unsigned long long ld_agent_u64(const unsigned long long* p) {
  return __hip_atomic_load(p, __ATOMIC_RELAXED, __HIP_MEMORY_SCOPE_AGENT);
}
__device__ __forceinline__ void st_agent_u64(unsigned long long* p, unsigned long long v) {
  __hip_atomic_store(p, v, __ATOMIC_RELAXED, __HIP_MEMORY_SCOPE_AGENT);
}

// ---- workspace init (runs every call; ws is NOT re-poisoned between replays)
__global__ void init_ws_kernel(unsigned long long* fvbuf, int* bmax) {
  int i = blockIdx.x * blockDim.x + threadIdx.x;
  if (i < 2 * K_TAGS) fvbuf[i] = 0ull;   // tag 0 everywhere
  if (i == 0) *bmax = 0;                 // float 0.0 bits; true max is positive
}

// ---- gates: one wave per step t; t==T_STEPS computes the terminal gate -----
__global__ __launch_bounds__(256) void gate_kernel(
    const float* __restrict__ reps, const float* __restrict__ wc,
    const float* __restrict__ wu, const int* __restrict__ spk,
    float* __restrict__ gate, float* __restrict__ g_term) {
  const int gw = (int)((blockIdx.x * blockDim.x + threadIdx.x) >> 6);  // wave id = t
  const int lane = threadIdx.x & 63;
  if (gw > T_STEPS) return;
  const int tcur = (gw < T_STEPS) ? gw : (T_STEPS - 1);
  const int tprv = (gw < T_STEPS) ? (gw > 0 ? gw - 1 : 0) : (T_STEPS - 1);
  const float* cur = reps + (size_t)tcur * D_DIM;
  const float* prv = reps + (size_t)tprv * D_DIM;
  float sc = 0.f, su = 0.f;
#pragma unroll
  for (int c = 0; c < 4; ++c) {
    const int d = lane * 4 + c * 256;
    float4 rp = *(const float4*)(prv + d);
    float4 rc = *(const float4*)(cur + d);
    float4 w1 = *(const float4*)(wc + d);
    float4 w2 = *(const float4*)(wc + D_DIM + d);
    float4 w3 = *(const float4*)(wu + d);
    float4 w4 = *(const float4*)(wu + D_DIM + d);
    sc += rp.x * w1.x + rp.y * w1.y + rp.z * w1.z + rp.w * w1.w;
    sc += rc.x * w2.x + rc.y * w2.y + rc.z * w2.z + rc.w * w2.w;
    su += rp.x * w3.x + rp.y * w3.y + rp.z * w3.z + rp.w * w3.w;
    su += rc.x * w4.x + rc.y * w4.y + rc.z * w4.z + rc.w * w4.w;
  }
#pragma unroll
  for (int off = 32; off; off >>= 1) {
    sc += __shfl_xor(sc, off);
    su += __shfl_xor(su, off);
  }
  if (lane == 0) {
    if (gw < T_STEPS) {
      bool uc = (gw > 0) && (spk[gw] != 0);
      float x = uc ? sc : su;
      gate[gw] = 1.0f / (1.0f + __expf(-x));
    } else {
      *g_term = 1.0f / (1.0f + __expf(-su));
    }
  }
}

// ---- global max over elementwise max(ti, ta) (for the safe LSE shift) ------
__global__ __launch_bounds__(256) void bmax_kernel(
    const float* __restrict__ ti, const float* __restrict__ ta, int* bmax) {
  size_t i = (size_t)blockIdx.x * blockDim.x + threadIdx.x;
  size_t n = (size_t)K_TAGS * K_TAGS;
  float m = 0.f;  // clamped at 0 so int-compare atomicMax is valid
  for (size_t j = i; j < n; j += (size_t)gridDim.x * blockDim.x)
    m = fmaxf(m, fmaxf(ti[j], ta[j]));
#pragma unroll
  for (int off = 32; off; off >>= 1) m = fmaxf(m, __shfl_xor(m, off));
  if ((threadIdx.x & 63) == 0) atomicMax(bmax, __float_as_int(m));
}

// ---- persistent CRF forward scan -------------------------------------------
// 256 blocks x 256 threads (4 waves). Wave w of block b owns row r=4b+w:
// 64 lanes x 16 prev cells, lane l owns prevs {2l + 128c : c=0..7}.
// Per step: poll 4 u64 tagged entries/thread -> LDS -> 1 barrier -> M2 from
// 4 broadcast words -> 16 exp2 cells -> wave shuffle-sum -> lane0 publishes.
// fv state exchanged via u64 (tag<<32 | float bits) relaxed agent atomics.
__global__ __launch_bounds__(256) void crf_kernel(
    const float* __restrict__ feats, const float* __restrict__ ti,
    const float* __restrict__ ta, const float* __restrict__ gate,
    const float* __restrict__ g_term_p, const int* __restrict__ bmax_p,
    unsigned long long* fvbuf, float* __restrict__ out) {
  const int b = blockIdx.x;
  const int tid = threadIdx.x;
  const int lane = tid & 63;
  const int w = tid >> 6;             // wave id = local row
  const int r = b * ROWS_PB + w;      // this wave's global row
  const int e0 = tid * 4;             // first of 4 gathered entries

  __shared__ __align__(16) float fvs[2][K_TAGS];
  __shared__ float wredM[4];
  __shared__ float wredS[4];

  // register-resident, log2-scaled matrix slices (constant across steps)
  float ta2[16], df2[16];
  {
    const float2* taP = reinterpret_cast<const float2*>(ta + (size_t)r * K_TAGS) + lane;
    const float2* tiP = reinterpret_cast<const float2*>(ti + (size_t)r * K_TAGS) + lane;
#pragma unroll
    for (int c = 0; c < C8; ++c) {
      float2 a = taP[64 * c];
      float2 i_ = tiP[64 * c];
      ta2[2 * c] = a.x * LOG2E;
      df2[2 * c] = (i_.x - a.x) * LOG2E;
      ta2[2 * c + 1] = a.y * LOG2E;
      df2[2 * c + 1] = (i_.y - a.y) * LOG2E;
    }
  }
  const float bmax2 = __int_as_float(*bmax_p) * LOG2E;

  // publish initial state s_0 (tag 1) into slot 0
  if (tid < ROWS_PB) {
    int rr = b * ROWS_PB + tid;
    float v = (rr == START_TAG) ? 0.0f : NEGV * LOG2E;
    st_agent_u64(&fvbuf[rr],
                 (1ull << 32) | (unsigned long long)__float_as_uint(v));
  }

  for (int t = 0; t < T_STEPS; ++t) {
    const int slot = t & 1;
    const unsigned want = (unsigned)(t + 1);
    const float g = gate[t];            // broadcast load, hidden under poll
    float featv = 0.f;
    if (lane == 0) featv = feats[(size_t)t * K_TAGS + r];

    // 1) gather: 4 independent tagged atoms per thread, tight poll
    unsigned long long* ep = &fvbuf[slot * K_TAGS + e0];
    unsigned long long u0 = ld_agent_u64(ep + 0);
    unsigned long long u1 = ld_agent_u64(ep + 1);
    unsigned long long u2 = ld_agent_u64(ep + 2);
    unsigned long long u3 = ld_agent_u64(ep + 3);
    while ((unsigned)(u0 >> 32) < want || (unsigned)(u1 >> 32) < want ||
           (unsigned)(u2 >> 32) < want || (unsigned)(u3 >> 32) < want) {
      u0 = ld_agent_u64(ep + 0);
      u1 = ld_agent_u64(ep + 1);
      u2 = ld_agent_u64(ep + 2);
      u3 = ld_agent_u64(ep + 3);
    }
    const float v0 = __uint_as_float((unsigned)u0);
    const float v1 = __uint_as_float((unsigned)u1);
    const float v2 = __uint_as_float((unsigned)u2);
    const float v3 = __uint_as_float((unsigned)u3);

    // 2) stash raw fv, wave-max -> one barrier
    *reinterpret_cast<float4*>(&fvs[slot][e0]) = make_float4(v0, v1, v2, v3);
    float m = fmaxf(fmaxf(v0, v1), fmaxf(v2, v3));
#pragma unroll
    for (int off = 32; off; off >>= 1) m = fmaxf(m, __shfl_xor(m, off));
    if (lane == 0) wredM[w] = m;
    __syncthreads();
    const float M2 =
        fmaxf(fmaxf(wredM[0], wredM[1]), fmaxf(wredM[2], wredM[3])) + bmax2;

    // 3) 16 cells/lane: acc += 2^(ta2 + g*df2 + fv - M2); conflict-free b64
    float acc = 0.f;
    const float2* fp = reinterpret_cast<const float2*>(&fvs[slot][0]) + lane;
#pragma unroll
    for (int c = 0; c < C8; ++c) {
      float2 f = fp[64 * c];
      acc += exp2f(__builtin_fmaf(g, df2[2 * c], ta2[2 * c]) + (f.x - M2));
      acc += exp2f(__builtin_fmaf(g, df2[2 * c + 1], ta2[2 * c + 1]) + (f.y - M2));
    }
#pragma unroll
    for (int off = 32; off; off >>= 1) acc += __shfl_xor(acc, off);

    // 4) lane0 finalizes + publishes (tag t+2) into the other slot
    if (lane == 0) {
      float fvnew = M2 + __log2f(acc) + featv * LOG2E;  // -inf if acc==0: OK
      st_agent_u64(&fvbuf[(slot ^ 1) * K_TAGS + r],
                   ((unsigned long long)(unsigned)(t + 2) << 32) |
                       (unsigned long long)__float_as_uint(fvnew));
    }
  }

  // ---- terminal LSE by block 0 ----------------------------------------------
  if (b == 0) {
    const unsigned want = (unsigned)(T_STEPS + 1);
    unsigned long long* ep = &fvbuf[(T_STEPS & 1) * K_TAGS + e0];
    unsigned long long u0 = ld_agent_u64(ep + 0);
    unsigned long long u1 = ld_agent_u64(ep + 1);
    unsigned long long u2 = ld_agent_u64(ep + 2);
    unsigned long long u3 = ld_agent_u64(ep + 3);
    while ((unsigned)(u0 >> 32) < want || (unsigned)(u1 >> 32) < want ||
           (unsigned)(u2 >> 32) < want || (unsigned)(u3 >> 32) < want) {
      u0 = ld_agent_u64(ep + 0);
      u1 = ld_agent_u64(ep + 1);
      u2 = ld_agent_u64(ep + 2);
      u3 = ld_agent_u64(ep + 3);
    }
    const float gt = *g_term_p;
    float term[4];
    const unsigned long long uu[4] = {u0, u1, u2, u3};
#pragma unroll
    for (int j = 0; j < 4; ++j) {
      const int k = e0 + j;
      float tis = ti[(size_t)STOP_TAG * K_TAGS + k];
      float tas = ta[(size_t)STOP_TAG * K_TAGS + k];
      term[j] = __uint_as_float((unsigned)uu[j]) +
                (tas + gt * (tis - tas)) * LOG2E;
    }
    float m = fmaxf(fmaxf(term[0], term[1]), fmaxf(term[2], term[3]));
#pragma unroll
    for (int off = 32; off; off >>= 1) m = fmaxf(m, __shfl_xor(m, off));
    if (lane == 0) wredM[w] = m;
    __syncthreads();
    const float M2 = fmaxf(fmaxf(wredM[0], wredM[1]), fmaxf(wredM[2], wredM[3]));
    float e = exp2f(term[0] - M2) + exp2f(term[1] - M2) +
              exp2f(term[2] - M2) + exp2f(term[3] - M2);
#pragma unroll
    for (int off = 32; off; off >>= 1) e += __shfl_xor(e, off);
    if (lane == 0) wredS[w] = e;
    __syncthreads();
    if (tid == 0) {
      float s = wredS[0] + wredS[1] + wredS[2] + wredS[3];
      out[0] = (M2 + __log2f(s)) * LN2;
    }
  }
}

extern "C" void kernel_launch(void* const* d_in, const int* in_sizes, int n_in,
                              void* d_out, int out_size, void* d_ws, size_t ws_size,
                              hipStream_t stream) {
  (void)in_sizes; (void)n_in; (void)out_size; (void)ws_size;
  const float* feats = (const float*)d_in[0];
  const float* reps  = (const float*)d_in[1];
  const float* wc    = (const float*)d_in[2];
  const float* wu    = (const float*)d_in[3];
  const float* ti    = (const float*)d_in[4];
  const float* ta    = (const float*)d_in[5];
  const int*   spk   = (const int*)d_in[6];
  float* out = (float*)d_out;

  // ws layout: fvbuf[2][1024] u64 (16 KiB) | gate[8192] f32 | g_term f32 | bmax i32
  unsigned long long* fvbuf = (unsigned long long*)d_ws;
  float* gate  = (float*)((char*)d_ws + 2 * K_TAGS * sizeof(unsigned long long));
  float* gterm = gate + T_STEPS;
  int*   bmax  = (int*)(gterm + 1);

  init_ws_kernel<<<dim3(8), dim3(256), 0, stream>>>(fvbuf, bmax);
  // 8193 wave-sized jobs, 4 waves per block
  gate_kernel<<<dim3((T_STEPS + 1 + 3) / 4), dim3(256), 0, stream>>>(
      reps, wc, wu, spk, gate, gterm);
  bmax_kernel<<<dim3(512), dim3(256), 0, stream>>>(ti, ta, bmax);
  crf_kernel<<<dim3(NBLK), dim3(256), 0, stream>>>(feats, ti, ta, gate, gterm,
                                                   bmax, fvbuf, out);
}